// Round 4
// baseline (2575.282 us; speedup 1.0000x reference)
//
#include <hip/hip_runtime.h>

#define NROWS 131072
#define KE 2048

typedef unsigned long long u64_t;
typedef unsigned int u32;

__device__ __forceinline__ unsigned f32_key(float f) {
  unsigned u = __float_as_uint(f);
  return (u & 0x80000000u) ? ~u : (u | 0x80000000u);
}

// async global -> LDS, 16 bytes per lane, dest = wave-uniform base + lane*16
__device__ __forceinline__ void gl_lds16(const float* g, const char* l) {
  __builtin_amdgcn_global_load_lds((const __attribute__((address_space(1))) u32*)g,
                                   (__attribute__((address_space(3))) u32*)l, 16, 0, 0);
}

// ---------------------------------------------------------------------------
// 64x64 tile f32 GEMM (UNCHANGED — enc1/dec2). MODE 0 only.
// ---------------------------------------------------------------------------
template <int MODE>
__global__ __launch_bounds__(256) void gemm64(
    const float* __restrict__ A, const float* __restrict__ B,
    const float* __restrict__ bias, float* __restrict__ C,
    int M, int N, int K,
    const int* __restrict__ gidx) {
  __shared__ __align__(16) float As[16][68];
  __shared__ __align__(16) float Bs[16][68];

  const int tid = threadIdx.x;
  const int tx = tid & 15;
  const int ty = tid >> 4;
  const int arow = blockIdx.x * 64;
  const int bcol = blockIdx.y * 64;

  const int lr = tid >> 2;
  const int lc = (tid & 3) * 4;
  int ga = arow + lr;
  if (MODE == 1) ga = gidx[ga];
  const float* Ap = A + (size_t)ga * K + lc;

  const int bkr = tid >> 4;
  const int bc4 = (tid & 15) * 4;
  const float* Bp = B + (size_t)bkr * N + bcol + bc4;

  float acc[4][4] = {};

  for (int kt = 0; kt < K; kt += 16) {
    float4 av = *reinterpret_cast<const float4*>(Ap);
    As[lc + 0][lr] = av.x;
    As[lc + 1][lr] = av.y;
    As[lc + 2][lr] = av.z;
    As[lc + 3][lr] = av.w;
    float4 bv = *reinterpret_cast<const float4*>(Bp);
    *reinterpret_cast<float4*>(&Bs[bkr][bc4]) = bv;
    Bp += (size_t)16 * N;
    Ap += 16;
    __syncthreads();
#pragma unroll
    for (int k = 0; k < 16; ++k) {
      float4 a = *reinterpret_cast<const float4*>(&As[k][ty * 4]);
      float4 b = *reinterpret_cast<const float4*>(&Bs[k][tx * 4]);
      acc[0][0] += a.x * b.x; acc[0][1] += a.x * b.y; acc[0][2] += a.x * b.z; acc[0][3] += a.x * b.w;
      acc[1][0] += a.y * b.x; acc[1][1] += a.y * b.y; acc[1][2] += a.y * b.z; acc[1][3] += a.y * b.w;
      acc[2][0] += a.z * b.x; acc[2][1] += a.z * b.y; acc[2][2] += a.z * b.z; acc[2][3] += a.z * b.w;
      acc[3][0] += a.w * b.x; acc[3][1] += a.w * b.y; acc[3][2] += a.w * b.z; acc[3][3] += a.w * b.w;
    }
    __syncthreads();
  }

#pragma unroll
  for (int i = 0; i < 4; ++i) {
    const int row = arow + ty * 4 + i;
    float4 v;
    v.x = fmaxf(acc[i][0] + bias[bcol + tx * 4 + 0], 0.f);
    v.y = fmaxf(acc[i][1] + bias[bcol + tx * 4 + 1], 0.f);
    v.z = fmaxf(acc[i][2] + bias[bcol + tx * 4 + 2], 0.f);
    v.w = fmaxf(acc[i][3] + bias[bcol + tx * 4 + 3], 0.f);
    *reinterpret_cast<float4*>(&C[(size_t)row * N + bcol + tx * 4]) = v;
  }
}

// ---------------------------------------------------------------------------
// 128x128 tile f32 GEMM (UNCHANGED from round 3 — enc2/enc3/dec1/dec3).
// Modes 0/1/2 only. z_e path must stay byte-identical.
// ---------------------------------------------------------------------------
template <int MODE>
__global__ __launch_bounds__(256) void gemm128(
    const float* __restrict__ A, const float* __restrict__ B,
    const float* __restrict__ bias, float* __restrict__ C,
    int N, int K,
    const int* __restrict__ gidx,
    const float* __restrict__ X,
    float* __restrict__ parts) {
  __shared__ __align__(16) char smem[17408];
  float (*As)[132] = (float(*)[132])smem;
  float (*Bs)[132] = (float(*)[132])(smem + 8448);

  const int tid = threadIdx.x;
  const int tx = tid & 15;
  const int ty = tid >> 4;
  const int arow = blockIdx.x * 128;
  const int bcol = blockIdx.y * 128;

  const int r0 = tid >> 2;
  const int r1 = r0 + 64;
  const int lc = (tid & 3) * 4;
  int ga0 = arow + r0, ga1 = arow + r1;
  if (MODE == 1) { ga0 = gidx[ga0]; ga1 = gidx[ga1]; }
  const float* Ap0 = A + (size_t)ga0 * K + lc;
  const float* Ap1 = A + (size_t)ga1 * K + lc;

  const int bk0 = tid >> 5;
  const int bc0 = (tid & 31) * 4;
  const float* Bp0 = B + (size_t)bk0 * N + bcol + bc0;
  const float* Bp1 = B + (size_t)(bk0 + 8) * N + bcol + bc0;

  float acc[8][8] = {};

  for (int kt = 0; kt < K; kt += 16) {
    float4 a0 = *reinterpret_cast<const float4*>(Ap0);
    float4 a1 = *reinterpret_cast<const float4*>(Ap1);
    As[lc + 0][r0] = a0.x; As[lc + 1][r0] = a0.y; As[lc + 2][r0] = a0.z; As[lc + 3][r0] = a0.w;
    As[lc + 0][r1] = a1.x; As[lc + 1][r1] = a1.y; As[lc + 2][r1] = a1.z; As[lc + 3][r1] = a1.w;
    float4 b0 = *reinterpret_cast<const float4*>(Bp0);
    float4 b1 = *reinterpret_cast<const float4*>(Bp1);
    *reinterpret_cast<float4*>(&Bs[bk0][bc0]) = b0;
    *reinterpret_cast<float4*>(&Bs[bk0 + 8][bc0]) = b1;
    Bp0 += (size_t)16 * N; Bp1 += (size_t)16 * N;
    Ap0 += 16; Ap1 += 16;
    __syncthreads();
#pragma unroll
    for (int k = 0; k < 16; ++k) {
      float4 av0 = *reinterpret_cast<const float4*>(&As[k][ty * 4]);
      float4 av1 = *reinterpret_cast<const float4*>(&As[k][64 + ty * 4]);
      float4 bv0 = *reinterpret_cast<const float4*>(&Bs[k][tx * 4]);
      float4 bv1 = *reinterpret_cast<const float4*>(&Bs[k][64 + tx * 4]);
      const float a[8] = {av0.x, av0.y, av0.z, av0.w, av1.x, av1.y, av1.z, av1.w};
      const float b[8] = {bv0.x, bv0.y, bv0.z, bv0.w, bv1.x, bv1.y, bv1.z, bv1.w};
#pragma unroll
      for (int i = 0; i < 8; ++i)
#pragma unroll
        for (int j = 0; j < 8; ++j) acc[i][j] += a[i] * b[j];
    }
    __syncthreads();
  }

  if (MODE == 0 || MODE == 1) {
#pragma unroll
    for (int i = 0; i < 8; ++i) {
      const int row = arow + (i >> 2) * 64 + ty * 4 + (i & 3);
      const int c0 = bcol + tx * 4;
      const int c1 = bcol + 64 + tx * 4;
      float4 v0, v1;
      v0.x = fmaxf(acc[i][0] + bias[c0 + 0], 0.f);
      v0.y = fmaxf(acc[i][1] + bias[c0 + 1], 0.f);
      v0.z = fmaxf(acc[i][2] + bias[c0 + 2], 0.f);
      v0.w = fmaxf(acc[i][3] + bias[c0 + 3], 0.f);
      v1.x = fmaxf(acc[i][4] + bias[c1 + 0], 0.f);
      v1.y = fmaxf(acc[i][5] + bias[c1 + 1], 0.f);
      v1.z = fmaxf(acc[i][6] + bias[c1 + 2], 0.f);
      v1.w = fmaxf(acc[i][7] + bias[c1 + 3], 0.f);
      *reinterpret_cast<float4*>(&C[(size_t)row * N + c0]) = v0;
      *reinterpret_cast<float4*>(&C[(size_t)row * N + c1]) = v1;
    }
  } else if (MODE == 2) {
    float local = 0.f;
#pragma unroll
    for (int i = 0; i < 8; ++i) {
      const int row = arow + (i >> 2) * 64 + ty * 4 + (i & 3);
#pragma unroll
      for (int j = 0; j < 8; ++j) {
        const int col = bcol + (j >> 2) * 64 + tx * 4 + (j & 3);
        float v = fmaxf(acc[i][j] + bias[col], 0.f);
        float d = v - X[(size_t)row * N + col];
        local += d * d;
      }
    }
    float* rbuf = (float*)smem;
    rbuf[tid] = local;
    __syncthreads();
    for (int off = 128; off > 0; off >>= 1) {
      if (tid < off) rbuf[tid] += rbuf[tid + off];
      __syncthreads();
    }
    if (tid == 0) parts[blockIdx.y * gridDim.x + blockIdx.x] = rbuf[0];
  }
}

// ---------------------------------------------------------------------------
// dist128: distance + argmin GEMM. 128x128 tile, K=256 fixed, BK=16, T=16.
// global_load_lds staging (linear dest), double-buffered LDS, prefetch issued
// BEFORE the FMA loop (T3-minimum 2-phase), one barrier per tile.
// LDS layout per operand: row r stored at slot L(r)=((r&3)<<5)|(r>>2), each
// slot = 4 chunks of 16B (4 consecutive k); chunk-slot XOR-swizzled by
// g=(L>>1)&3, applied on BOTH global source and LDS read (involution).
// Per-acc-element accumulation strictly ascending k -> bit-identical scores.
// ---------------------------------------------------------------------------
__global__ __launch_bounds__(256) void dist128(
    const float* __restrict__ A,   // z_e [NROWS][256]
    const float* __restrict__ B,   // emb [KE][256]
    const float* __restrict__ zsq,
    const float* __restrict__ esq,
    u64_t* __restrict__ keys) {
  __shared__ __align__(16) char smem[32768];  // 2 buffers x (A 8192 + B 8192)

  const int tid = threadIdx.x;
  const int tx = tid & 15;
  const int ty = tid >> 4;
  const int arow = blockIdx.x * 128;
  const int bcol = blockIdx.y * 128;
  const int l = tid & 63;
  const int w = tid >> 6;

  // --- staging: per-thread global pointers (pre-swizzled source) ---
  const int S0 = w * 16 + (l >> 2);            // LDS slot for issue 0
  const int c  = l & 3;                         // chunk-slot within row
  const int R0 = ((S0 & 31) << 2) | (S0 >> 5); // global row for slot S0
  const int g0 = (S0 >> 1) & 3;                 // swizzle (same for S0+64)
  const int R1 = R0 + 2;                        // global row for slot S0+64
  const int ck = (c ^ g0) << 2;                 // swizzled k-chunk (floats)
  const float* gA0 = A + (size_t)(arow + R0) * 256 + ck;
  const float* gA1 = A + (size_t)(arow + R1) * 256 + ck;
  const float* gB0 = B + (size_t)(bcol + R0) * 256 + ck;
  const float* gB1 = B + (size_t)(bcol + R1) * 256 + ck;

  // wave-uniform LDS dest offsets (within a buffer)
  const int dA0 = w * 1024;
  const int dA1 = 4096 + w * 1024;
  const int dB0 = 8192 + w * 1024;
  const int dB1 = 12288 + w * 1024;

  // --- fragment read offsets (byte, buffer-relative, swizzle folded in) ---
  int offA[8], offB[8];
#pragma unroll
  for (int i = 0; i < 8; ++i) {
    const int ar = (i >> 2) * 64 + ty * 4 + (i & 3);
    const int La = ((ar & 3) << 5) | (ar >> 2);
    offA[i] = La * 64 + (((La >> 1) & 3) << 4);
    const int bc = (i >> 2) * 64 + tx * 4 + (i & 3);
    const int Lb = ((bc & 3) << 5) | (bc >> 2);
    offB[i] = 8192 + Lb * 64 + (((Lb >> 1) & 3) << 4);
  }

  float acc[8][8] = {};

  // prologue: stage tile 0 into buffer 0
  gl_lds16(gA0, smem + dA0);
  gl_lds16(gA1, smem + dA1);
  gl_lds16(gB0, smem + dB0);
  gl_lds16(gB1, smem + dB1);
  gA0 += 16; gA1 += 16; gB0 += 16; gB1 += 16;
  __syncthreads();

  for (int t = 0; t < 16; ++t) {
    const int bo = (t & 1) << 14;  // 0 / 16384
    if (t < 15) {
      const int nbo = bo ^ 16384;
      gl_lds16(gA0, smem + nbo + dA0);
      gl_lds16(gA1, smem + nbo + dA1);
      gl_lds16(gB0, smem + nbo + dB0);
      gl_lds16(gB1, smem + nbo + dB1);
      gA0 += 16; gA1 += 16; gB0 += 16; gB1 += 16;
    }
#pragma unroll
    for (int kq = 0; kq < 4; ++kq) {
      const int mask = bo | (kq << 4);  // bits disjoint: XOR == ADD per field
      float4 bq[8];
#pragma unroll
      for (int j = 0; j < 8; ++j)
        bq[j] = *reinterpret_cast<const float4*>(smem + (offB[j] ^ mask));
#pragma unroll
      for (int i = 0; i < 8; ++i) {
        const float4 aq = *reinterpret_cast<const float4*>(smem + (offA[i] ^ mask));
#pragma unroll
        for (int kk = 0; kk < 4; ++kk) {   // k = 16t + 4kq + kk, ascending
          const float av = (&aq.x)[kk];
#pragma unroll
          for (int j = 0; j < 8; ++j)
            acc[i][j] += av * (&bq[j].x)[kk];
        }
      }
    }
    __syncthreads();  // drains vmcnt -> next buffer staged & visible
  }

  // epilogue: scores + per-block argmin (identical logic to round 3)
  u64_t (*mb)[17] = (u64_t(*)[17])smem;  // 17408 B, safe after final barrier
#pragma unroll
  for (int i = 0; i < 8; ++i) {
    const int row = (i >> 2) * 64 + ty * 4 + (i & 3);
    const float zs = zsq[arow + row];
    u64_t best = ~0ull;
#pragma unroll
    for (int j = 0; j < 8; ++j) {
      const int col = bcol + (j >> 2) * 64 + tx * 4 + (j & 3);
      // exact reference rounding: (z_sq - 2*p) + e_sq  (2*p exact in fp)
      float dsc = (zs - 2.0f * acc[i][j]) + esq[col];
      u64_t kk = ((u64_t)f32_key(dsc) << 32) | (unsigned)col;
      if (kk < best) best = kk;
    }
    mb[row][tx] = best;
  }
  __syncthreads();
  if (tid < 128) {
    u64_t b = mb[tid][0];
#pragma unroll
    for (int t2 = 1; t2 < 16; ++t2) {
      u64_t v = mb[tid][t2];
      if (v < b) b = v;
    }
    atomicMin(&keys[arow + tid], b);
  }
}

// sum of squares per row (256 cols); block = 4 rows x 64 lanes
__global__ __launch_bounds__(256) void rowsq(const float* __restrict__ src,
                                             float* __restrict__ dst, int rows) {
  const int sub = threadIdx.x >> 6;
  const int lane = threadIdx.x & 63;
  const int r = blockIdx.x * 4 + sub;
  if (r >= rows) return;
  const float* p = src + (size_t)r * 256;
  float s = 0.f;
#pragma unroll
  for (int j = 0; j < 4; ++j) {
    float v = p[lane + 64 * j];
    s += v * v;
  }
#pragma unroll
  for (int off = 32; off > 0; off >>= 1) s += __shfl_down(s, off, 64);
  if (lane == 0) dst[r] = s;
}

__global__ __launch_bounds__(256) void init_keys(u64_t* __restrict__ keys) {
  keys[(size_t)blockIdx.x * 256 + threadIdx.x] = ~0ull;
}

// per row: idx from key, write z_latent = z + (e - z), quant-loss partial sums
__global__ __launch_bounds__(256) void gather_quant(
    const u64_t* __restrict__ keys, const float* __restrict__ emb,
    const float* __restrict__ z_e, float* __restrict__ zlat,
    int* __restrict__ idx_out, float* __restrict__ qparts) {
  const int sub = threadIdx.x >> 6;
  const int lane = threadIdx.x & 63;
  const int r = blockIdx.x * 4 + sub;
  const int idx = (int)(keys[r] & 0xFFFFFFFFull);
  if (lane == 0) idx_out[r] = idx;
  float s = 0.f;
#pragma unroll
  for (int j = 0; j < 4; ++j) {
    const int d = lane + 64 * j;
    float e = emb[(size_t)idx * 256 + d];
    float z = z_e[(size_t)r * 256 + d];
    float df = e - z;
    s += df * df;
    zlat[(size_t)r * 256 + d] = z + df;  // fl(z_e + fl(z_q - z_e)) — exact ref order
  }
#pragma unroll
  for (int off = 32; off > 0; off >>= 1) s += __shfl_down(s, off, 64);
  __shared__ float red[4];
  if (lane == 0) red[sub] = s;
  __syncthreads();
  if (threadIdx.x == 0) qparts[blockIdx.x] = (red[0] + red[1]) + (red[2] + red[3]);
}

__global__ __launch_bounds__(256) void final_loss(
    const float* __restrict__ qparts, int nq,
    const float* __restrict__ rparts, int nr, float* __restrict__ out) {
  const int tid = threadIdx.x;
  double sq = 0.0, sr = 0.0;
  for (int i = tid; i < nq; i += 256) sq += (double)qparts[i];
  for (int i = tid; i < nr; i += 256) sr += (double)rparts[i];
  __shared__ double bq[256], br[256];
  bq[tid] = sq;
  br[tid] = sr;
  __syncthreads();
  for (int off = 128; off > 0; off >>= 1) {
    if (tid < off) {
      bq[tid] += bq[tid + off];
      br[tid] += br[tid + off];
    }
    __syncthreads();
  }
  if (tid == 0) {
    double qm = bq[0] / ((double)NROWS * 256.0);
    double rm = br[0] / ((double)NROWS * 512.0);
    out[(size_t)NROWS * 256] = (float)(rm + 1.25 * qm);  // recon + (1+BETA)*quant
  }
}

extern "C" void kernel_launch(void* const* d_in, const int* in_sizes, int n_in,
                              void* d_out, int out_size, void* d_ws, size_t ws_size,
                              hipStream_t stream) {
  const float* x   = (const float*)d_in[0];
  const float* ew1 = (const float*)d_in[1];
  const float* eb1 = (const float*)d_in[2];
  const float* ew2 = (const float*)d_in[3];
  const float* eb2 = (const float*)d_in[4];
  const float* ew3 = (const float*)d_in[5];
  const float* eb3 = (const float*)d_in[6];
  const float* dw1 = (const float*)d_in[7];
  const float* db1 = (const float*)d_in[8];
  const float* dw2 = (const float*)d_in[9];
  const float* db2 = (const float*)d_in[10];
  const float* dw3 = (const float*)d_in[11];
  const float* db3 = (const float*)d_in[12];
  const float* emb = (const float*)d_in[13];

  char* ws = (char*)d_ws;
  float* h1     = (float*)(ws);                    // N x 64   (reused as dec h2)
  float* h2     = (float*)(ws + 33554432ull);      // N x 128  (reused as dec h1)
  float* z_e    = (float*)(ws + 100663296ull);     // N x 256
  float* zsq    = (float*)(ws + 234881024ull);     // N
  float* esq    = (float*)(ws + 235405312ull);     // KE
  u64_t* keys   = (u64_t*)(ws + 235413504ull);     // N
  int* idx      = (int*)(ws + 236462080ull);       // N
  float* qparts = (float*)(ws + 236986368ull);     // N/4 = 32768
  float* rparts = (float*)(ws + 237117440ull);     // 1024*4 = 4096

  float* out = (float*)d_out;

  dim3 blk(256);

  // encoder: 512 -> 64 -> 128 -> 256  (all unchanged -> bit-exact z_e)
  gemm64<0><<<dim3(NROWS / 64, 1), blk, 0, stream>>>(x, ew1, eb1, h1, NROWS, 64, 512,
      nullptr);
  gemm128<0><<<dim3(NROWS / 128, 1), blk, 0, stream>>>(h1, ew2, eb2, h2,
      128, 64, nullptr, nullptr, nullptr);
  gemm128<0><<<dim3(NROWS / 128, 2), blk, 0, stream>>>(h2, ew3, eb3, z_e,
      256, 128, nullptr, nullptr, nullptr);

  rowsq<<<dim3(NROWS / 4), blk, 0, stream>>>(z_e, zsq, NROWS);
  rowsq<<<dim3(KE / 4), blk, 0, stream>>>(emb, esq, KE);
  init_keys<<<dim3(NROWS / 256), blk, 0, stream>>>(keys);

  // distances + argmin: pipelined global_load_lds kernel, bit-identical scores
  dist128<<<dim3(NROWS / 128, KE / 128), blk, 0, stream>>>(z_e, emb, zsq, esq, keys);

  gather_quant<<<dim3(NROWS / 4), blk, 0, stream>>>(keys, emb, z_e, out, idx, qparts);

  // decoder: 256 -> 128 -> 64 -> 512 (loss-only path, 2% threshold)
  gemm128<1><<<dim3(NROWS / 128, 1), blk, 0, stream>>>(emb, dw1, db1, h2,
      128, 256, idx, nullptr, nullptr);
  gemm64<0><<<dim3(NROWS / 64, 1), blk, 0, stream>>>(h2, dw2, db2, h1, NROWS, 64, 128,
      nullptr);
  gemm128<2><<<dim3(NROWS / 128, 4), blk, 0, stream>>>(h1, dw3, db3, nullptr,
      512, 64, nullptr, x, rparts);

  final_loss<<<dim3(1), blk, 0, stream>>>(qparts, NROWS / 4, rparts, 4096, out);
}

// Round 5
// 2305.160 us; speedup vs baseline: 1.1172x; 1.1172x over previous
//
#include <hip/hip_runtime.h>

#define NROWS 131072
#define KE 2048

typedef unsigned long long u64_t;

__device__ __forceinline__ unsigned f32_key(float f) {
  unsigned u = __float_as_uint(f);
  return (u & 0x80000000u) ? ~u : (u | 0x80000000u);
}

// ---------------------------------------------------------------------------
// 64x64 tile f32 GEMM (UNCHANGED — enc1/dec2). MODE 0 only.
// ---------------------------------------------------------------------------
template <int MODE>
__global__ __launch_bounds__(256) void gemm64(
    const float* __restrict__ A, const float* __restrict__ B,
    const float* __restrict__ bias, float* __restrict__ C,
    int M, int N, int K,
    const int* __restrict__ gidx) {
  __shared__ __align__(16) float As[16][68];
  __shared__ __align__(16) float Bs[16][68];

  const int tid = threadIdx.x;
  const int tx = tid & 15;
  const int ty = tid >> 4;
  const int arow = blockIdx.x * 64;
  const int bcol = blockIdx.y * 64;

  const int lr = tid >> 2;
  const int lc = (tid & 3) * 4;
  int ga = arow + lr;
  if (MODE == 1) ga = gidx[ga];
  const float* Ap = A + (size_t)ga * K + lc;

  const int bkr = tid >> 4;
  const int bc4 = (tid & 15) * 4;
  const float* Bp = B + (size_t)bkr * N + bcol + bc4;

  float acc[4][4] = {};

  for (int kt = 0; kt < K; kt += 16) {
    float4 av = *reinterpret_cast<const float4*>(Ap);
    As[lc + 0][lr] = av.x;
    As[lc + 1][lr] = av.y;
    As[lc + 2][lr] = av.z;
    As[lc + 3][lr] = av.w;
    float4 bv = *reinterpret_cast<const float4*>(Bp);
    *reinterpret_cast<float4*>(&Bs[bkr][bc4]) = bv;
    Bp += (size_t)16 * N;
    Ap += 16;
    __syncthreads();
#pragma unroll
    for (int k = 0; k < 16; ++k) {
      float4 a = *reinterpret_cast<const float4*>(&As[k][ty * 4]);
      float4 b = *reinterpret_cast<const float4*>(&Bs[k][tx * 4]);
      acc[0][0] += a.x * b.x; acc[0][1] += a.x * b.y; acc[0][2] += a.x * b.z; acc[0][3] += a.x * b.w;
      acc[1][0] += a.y * b.x; acc[1][1] += a.y * b.y; acc[1][2] += a.y * b.z; acc[1][3] += a.y * b.w;
      acc[2][0] += a.z * b.x; acc[2][1] += a.z * b.y; acc[2][2] += a.z * b.z; acc[2][3] += a.z * b.w;
      acc[3][0] += a.w * b.x; acc[3][1] += a.w * b.y; acc[3][2] += a.w * b.z; acc[3][3] += a.w * b.w;
    }
    __syncthreads();
  }

#pragma unroll
  for (int i = 0; i < 4; ++i) {
    const int row = arow + ty * 4 + i;
    float4 v;
    v.x = fmaxf(acc[i][0] + bias[bcol + tx * 4 + 0], 0.f);
    v.y = fmaxf(acc[i][1] + bias[bcol + tx * 4 + 1], 0.f);
    v.z = fmaxf(acc[i][2] + bias[bcol + tx * 4 + 2], 0.f);
    v.w = fmaxf(acc[i][3] + bias[bcol + tx * 4 + 3], 0.f);
    *reinterpret_cast<float4*>(&C[(size_t)row * N + bcol + tx * 4]) = v;
  }
}

// ---------------------------------------------------------------------------
// 128x128 tile f32 GEMM (UNCHANGED — enc2/enc3/dec1/dec3). Modes 0/1/2.
// ---------------------------------------------------------------------------
template <int MODE>
__global__ __launch_bounds__(256) void gemm128(
    const float* __restrict__ A, const float* __restrict__ B,
    const float* __restrict__ bias, float* __restrict__ C,
    int N, int K,
    const int* __restrict__ gidx,
    const float* __restrict__ X,
    float* __restrict__ parts) {
  __shared__ __align__(16) char smem[17408];
  float (*As)[132] = (float(*)[132])smem;
  float (*Bs)[132] = (float(*)[132])(smem + 8448);

  const int tid = threadIdx.x;
  const int tx = tid & 15;
  const int ty = tid >> 4;
  const int arow = blockIdx.x * 128;
  const int bcol = blockIdx.y * 128;

  const int r0 = tid >> 2;
  const int r1 = r0 + 64;
  const int lc = (tid & 3) * 4;
  int ga0 = arow + r0, ga1 = arow + r1;
  if (MODE == 1) { ga0 = gidx[ga0]; ga1 = gidx[ga1]; }
  const float* Ap0 = A + (size_t)ga0 * K + lc;
  const float* Ap1 = A + (size_t)ga1 * K + lc;

  const int bk0 = tid >> 5;
  const int bc0 = (tid & 31) * 4;
  const float* Bp0 = B + (size_t)bk0 * N + bcol + bc0;
  const float* Bp1 = B + (size_t)(bk0 + 8) * N + bcol + bc0;

  float acc[8][8] = {};

  for (int kt = 0; kt < K; kt += 16) {
    float4 a0 = *reinterpret_cast<const float4*>(Ap0);
    float4 a1 = *reinterpret_cast<const float4*>(Ap1);
    As[lc + 0][r0] = a0.x; As[lc + 1][r0] = a0.y; As[lc + 2][r0] = a0.z; As[lc + 3][r0] = a0.w;
    As[lc + 0][r1] = a1.x; As[lc + 1][r1] = a1.y; As[lc + 2][r1] = a1.z; As[lc + 3][r1] = a1.w;
    float4 b0 = *reinterpret_cast<const float4*>(Bp0);
    float4 b1 = *reinterpret_cast<const float4*>(Bp1);
    *reinterpret_cast<float4*>(&Bs[bk0][bc0]) = b0;
    *reinterpret_cast<float4*>(&Bs[bk0 + 8][bc0]) = b1;
    Bp0 += (size_t)16 * N; Bp1 += (size_t)16 * N;
    Ap0 += 16; Ap1 += 16;
    __syncthreads();
#pragma unroll
    for (int k = 0; k < 16; ++k) {
      float4 av0 = *reinterpret_cast<const float4*>(&As[k][ty * 4]);
      float4 av1 = *reinterpret_cast<const float4*>(&As[k][64 + ty * 4]);
      float4 bv0 = *reinterpret_cast<const float4*>(&Bs[k][tx * 4]);
      float4 bv1 = *reinterpret_cast<const float4*>(&Bs[k][64 + tx * 4]);
      const float a[8] = {av0.x, av0.y, av0.z, av0.w, av1.x, av1.y, av1.z, av1.w};
      const float b[8] = {bv0.x, bv0.y, bv0.z, bv0.w, bv1.x, bv1.y, bv1.z, bv1.w};
#pragma unroll
      for (int i = 0; i < 8; ++i)
#pragma unroll
        for (int j = 0; j < 8; ++j) acc[i][j] += a[i] * b[j];
    }
    __syncthreads();
  }

  if (MODE == 0 || MODE == 1) {
#pragma unroll
    for (int i = 0; i < 8; ++i) {
      const int row = arow + (i >> 2) * 64 + ty * 4 + (i & 3);
      const int c0 = bcol + tx * 4;
      const int c1 = bcol + 64 + tx * 4;
      float4 v0, v1;
      v0.x = fmaxf(acc[i][0] + bias[c0 + 0], 0.f);
      v0.y = fmaxf(acc[i][1] + bias[c0 + 1], 0.f);
      v0.z = fmaxf(acc[i][2] + bias[c0 + 2], 0.f);
      v0.w = fmaxf(acc[i][3] + bias[c0 + 3], 0.f);
      v1.x = fmaxf(acc[i][4] + bias[c1 + 0], 0.f);
      v1.y = fmaxf(acc[i][5] + bias[c1 + 1], 0.f);
      v1.z = fmaxf(acc[i][6] + bias[c1 + 2], 0.f);
      v1.w = fmaxf(acc[i][7] + bias[c1 + 3], 0.f);
      *reinterpret_cast<float4*>(&C[(size_t)row * N + c0]) = v0;
      *reinterpret_cast<float4*>(&C[(size_t)row * N + c1]) = v1;
    }
  } else if (MODE == 2) {
    float local = 0.f;
#pragma unroll
    for (int i = 0; i < 8; ++i) {
      const int row = arow + (i >> 2) * 64 + ty * 4 + (i & 3);
#pragma unroll
      for (int j = 0; j < 8; ++j) {
        const int col = bcol + (j >> 2) * 64 + tx * 4 + (j & 3);
        float v = fmaxf(acc[i][j] + bias[col], 0.f);
        float d = v - X[(size_t)row * N + col];
        local += d * d;
      }
    }
    float* rbuf = (float*)smem;
    rbuf[tid] = local;
    __syncthreads();
    for (int off = 128; off > 0; off >>= 1) {
      if (tid < off) rbuf[tid] += rbuf[tid + off];
      __syncthreads();
    }
    if (tid == 0) parts[blockIdx.y * gridDim.x + blockIdx.x] = rbuf[0];
  }
}

// ---------------------------------------------------------------------------
// dist64: distance + argmin. 128 rows x 64 cols per block, 256 threads,
// per-thread 8 rows x 4 cols (32 acc). Live set ~60 VGPR -> 8 waves/SIMD.
// LDS 17.4 KB. A-reads broadcast, B-reads 16B-stride (2-way, free).
// blockIdx.x = col-tile (fast) so a row-tile's 32 blocks share the A-tile
// and emb (2 MB) stays L2-resident.
// Per-acc-element accumulation strictly ascending k -> bit-identical scores.
// ---------------------------------------------------------------------------
__global__ __launch_bounds__(256) void dist64(
    const float* __restrict__ A,   // z_e [NROWS][256]
    const float* __restrict__ B,   // emb [KE][256]
    const float* __restrict__ zsq,
    const float* __restrict__ esq,
    u64_t* __restrict__ keys) {
  __shared__ __align__(16) char smem[17408];
  float (*As)[132] = (float(*)[132])smem;          // 16 x 132 * 4 = 8448 B
  float (*Bs)[68]  = (float(*)[68])(smem + 8448);  // 16 x 68 * 4 = 4352 B

  const int tid = threadIdx.x;
  const int tx = tid & 15;
  const int ty = tid >> 4;
  const int bcol = blockIdx.x * 64;
  const int arow = blockIdx.y * 128;

  // staging: A two float4/thread, B one float4/thread; transposed scatter
  const int r0 = tid >> 2;        // 0..63
  const int r1 = r0 + 64;
  const int lc = (tid & 3) * 4;   // 0,4,8,12
  const float* Ap0 = A + (size_t)(arow + r0) * 256 + lc;
  const float* Ap1 = A + (size_t)(arow + r1) * 256 + lc;
  const float* Bp  = B + (size_t)(bcol + r0) * 256 + lc;  // emb rows = codes

  float acc[8][4] = {};

  for (int kt = 0; kt < 256; kt += 16) {
    float4 a0 = *reinterpret_cast<const float4*>(Ap0);
    float4 a1 = *reinterpret_cast<const float4*>(Ap1);
    float4 b0 = *reinterpret_cast<const float4*>(Bp);
    As[lc + 0][r0] = a0.x; As[lc + 1][r0] = a0.y; As[lc + 2][r0] = a0.z; As[lc + 3][r0] = a0.w;
    As[lc + 0][r1] = a1.x; As[lc + 1][r1] = a1.y; As[lc + 2][r1] = a1.z; As[lc + 3][r1] = a1.w;
    Bs[lc + 0][r0] = b0.x; Bs[lc + 1][r0] = b0.y; Bs[lc + 2][r0] = b0.z; Bs[lc + 3][r0] = b0.w;
    Ap0 += 16; Ap1 += 16; Bp += 16;
    __syncthreads();
#pragma unroll
    for (int k = 0; k < 16; ++k) {
      float4 av0 = *reinterpret_cast<const float4*>(&As[k][ty * 4]);
      float4 av1 = *reinterpret_cast<const float4*>(&As[k][64 + ty * 4]);
      float4 bv  = *reinterpret_cast<const float4*>(&Bs[k][tx * 4]);
      acc[0][0] += av0.x * bv.x; acc[0][1] += av0.x * bv.y; acc[0][2] += av0.x * bv.z; acc[0][3] += av0.x * bv.w;
      acc[1][0] += av0.y * bv.x; acc[1][1] += av0.y * bv.y; acc[1][2] += av0.y * bv.z; acc[1][3] += av0.y * bv.w;
      acc[2][0] += av0.z * bv.x; acc[2][1] += av0.z * bv.y; acc[2][2] += av0.z * bv.z; acc[2][3] += av0.z * bv.w;
      acc[3][0] += av0.w * bv.x; acc[3][1] += av0.w * bv.y; acc[3][2] += av0.w * bv.z; acc[3][3] += av0.w * bv.w;
      acc[4][0] += av1.x * bv.x; acc[4][1] += av1.x * bv.y; acc[4][2] += av1.x * bv.z; acc[4][3] += av1.x * bv.w;
      acc[5][0] += av1.y * bv.x; acc[5][1] += av1.y * bv.y; acc[5][2] += av1.y * bv.z; acc[5][3] += av1.y * bv.w;
      acc[6][0] += av1.z * bv.x; acc[6][1] += av1.z * bv.y; acc[6][2] += av1.z * bv.z; acc[6][3] += av1.z * bv.w;
      acc[7][0] += av1.w * bv.x; acc[7][1] += av1.w * bv.y; acc[7][2] += av1.w * bv.z; acc[7][3] += av1.w * bv.w;
    }
    __syncthreads();
  }

  // epilogue: scores + per-block argmin (same exact rounding as before)
  u64_t (*mb)[17] = (u64_t(*)[17])smem;  // 128 x 17 x 8 = 17408 B
#pragma unroll
  for (int i = 0; i < 8; ++i) {
    const int row = (i >> 2) * 64 + ty * 4 + (i & 3);
    const float zs = zsq[arow + row];
    u64_t best = ~0ull;
#pragma unroll
    for (int j = 0; j < 4; ++j) {
      const int col = bcol + tx * 4 + j;
      // exact reference rounding: (z_sq - 2*p) + e_sq  (2*p exact in fp)
      float dsc = (zs - 2.0f * acc[i][j]) + esq[col];
      u64_t kk = ((u64_t)f32_key(dsc) << 32) | (unsigned)col;
      if (kk < best) best = kk;
    }
    mb[row][tx] = best;
  }
  __syncthreads();
  if (tid < 128) {
    u64_t b = mb[tid][0];
#pragma unroll
    for (int t2 = 1; t2 < 16; ++t2) {
      u64_t v = mb[tid][t2];
      if (v < b) b = v;
    }
    atomicMin(&keys[arow + tid], b);
  }
}

// sum of squares per row (256 cols); block = 4 rows x 64 lanes
__global__ __launch_bounds__(256) void rowsq(const float* __restrict__ src,
                                             float* __restrict__ dst, int rows) {
  const int sub = threadIdx.x >> 6;
  const int lane = threadIdx.x & 63;
  const int r = blockIdx.x * 4 + sub;
  if (r >= rows) return;
  const float* p = src + (size_t)r * 256;
  float s = 0.f;
#pragma unroll
  for (int j = 0; j < 4; ++j) {
    float v = p[lane + 64 * j];
    s += v * v;
  }
#pragma unroll
  for (int off = 32; off > 0; off >>= 1) s += __shfl_down(s, off, 64);
  if (lane == 0) dst[r] = s;
}

__global__ __launch_bounds__(256) void init_keys(u64_t* __restrict__ keys) {
  keys[(size_t)blockIdx.x * 256 + threadIdx.x] = ~0ull;
}

// per row: idx from key, write z_latent = z + (e - z), quant-loss partial sums
__global__ __launch_bounds__(256) void gather_quant(
    const u64_t* __restrict__ keys, const float* __restrict__ emb,
    const float* __restrict__ z_e, float* __restrict__ zlat,
    int* __restrict__ idx_out, float* __restrict__ qparts) {
  const int sub = threadIdx.x >> 6;
  const int lane = threadIdx.x & 63;
  const int r = blockIdx.x * 4 + sub;
  const int idx = (int)(keys[r] & 0xFFFFFFFFull);
  if (lane == 0) idx_out[r] = idx;
  float s = 0.f;
#pragma unroll
  for (int j = 0; j < 4; ++j) {
    const int d = lane + 64 * j;
    float e = emb[(size_t)idx * 256 + d];
    float z = z_e[(size_t)r * 256 + d];
    float df = e - z;
    s += df * df;
    zlat[(size_t)r * 256 + d] = z + df;  // fl(z_e + fl(z_q - z_e)) — exact ref order
  }
#pragma unroll
  for (int off = 32; off > 0; off >>= 1) s += __shfl_down(s, off, 64);
  __shared__ float red[4];
  if (lane == 0) red[sub] = s;
  __syncthreads();
  if (threadIdx.x == 0) qparts[blockIdx.x] = (red[0] + red[1]) + (red[2] + red[3]);
}

__global__ __launch_bounds__(256) void final_loss(
    const float* __restrict__ qparts, int nq,
    const float* __restrict__ rparts, int nr, float* __restrict__ out) {
  const int tid = threadIdx.x;
  double sq = 0.0, sr = 0.0;
  for (int i = tid; i < nq; i += 256) sq += (double)qparts[i];
  for (int i = tid; i < nr; i += 256) sr += (double)rparts[i];
  __shared__ double bq[256], br[256];
  bq[tid] = sq;
  br[tid] = sr;
  __syncthreads();
  for (int off = 128; off > 0; off >>= 1) {
    if (tid < off) {
      bq[tid] += bq[tid + off];
      br[tid] += br[tid + off];
    }
    __syncthreads();
  }
  if (tid == 0) {
    double qm = bq[0] / ((double)NROWS * 256.0);
    double rm = br[0] / ((double)NROWS * 512.0);
    out[(size_t)NROWS * 256] = (float)(rm + 1.25 * qm);  // recon + (1+BETA)*quant
  }
}

extern "C" void kernel_launch(void* const* d_in, const int* in_sizes, int n_in,
                              void* d_out, int out_size, void* d_ws, size_t ws_size,
                              hipStream_t stream) {
  const float* x   = (const float*)d_in[0];
  const float* ew1 = (const float*)d_in[1];
  const float* eb1 = (const float*)d_in[2];
  const float* ew2 = (const float*)d_in[3];
  const float* eb2 = (const float*)d_in[4];
  const float* ew3 = (const float*)d_in[5];
  const float* eb3 = (const float*)d_in[6];
  const float* dw1 = (const float*)d_in[7];
  const float* db1 = (const float*)d_in[8];
  const float* dw2 = (const float*)d_in[9];
  const float* db2 = (const float*)d_in[10];
  const float* dw3 = (const float*)d_in[11];
  const float* db3 = (const float*)d_in[12];
  const float* emb = (const float*)d_in[13];

  char* ws = (char*)d_ws;
  float* h1     = (float*)(ws);                    // N x 64   (reused as dec h2)
  float* h2     = (float*)(ws + 33554432ull);      // N x 128  (reused as dec h1)
  float* z_e    = (float*)(ws + 100663296ull);     // N x 256
  float* zsq    = (float*)(ws + 234881024ull);     // N
  float* esq    = (float*)(ws + 235405312ull);     // KE
  u64_t* keys   = (u64_t*)(ws + 235413504ull);     // N
  int* idx      = (int*)(ws + 236462080ull);       // N
  float* qparts = (float*)(ws + 236986368ull);     // N/4 = 32768
  float* rparts = (float*)(ws + 237117440ull);     // 1024*4 = 4096

  float* out = (float*)d_out;

  dim3 blk(256);

  // encoder: 512 -> 64 -> 128 -> 256  (all unchanged -> bit-exact z_e)
  gemm64<0><<<dim3(NROWS / 64, 1), blk, 0, stream>>>(x, ew1, eb1, h1, NROWS, 64, 512,
      nullptr);
  gemm128<0><<<dim3(NROWS / 128, 1), blk, 0, stream>>>(h1, ew2, eb2, h2,
      128, 64, nullptr, nullptr, nullptr);
  gemm128<0><<<dim3(NROWS / 128, 2), blk, 0, stream>>>(h2, ew3, eb3, z_e,
      256, 128, nullptr, nullptr, nullptr);

  rowsq<<<dim3(NROWS / 4), blk, 0, stream>>>(z_e, zsq, NROWS);
  rowsq<<<dim3(KE / 4), blk, 0, stream>>>(emb, esq, KE);
  init_keys<<<dim3(NROWS / 256), blk, 0, stream>>>(keys);

  // distances + argmin: 128x64 blocks, col-tile-fast grid, bit-identical scores
  dist64<<<dim3(KE / 64, NROWS / 128), blk, 0, stream>>>(z_e, emb, zsq, esq, keys);

  gather_quant<<<dim3(NROWS / 4), blk, 0, stream>>>(keys, emb, z_e, out, idx, qparts);

  // decoder: 256 -> 128 -> 64 -> 512 (loss-only path, 2% threshold)
  gemm128<1><<<dim3(NROWS / 128, 1), blk, 0, stream>>>(emb, dw1, db1, h2,
      128, 256, idx, nullptr, nullptr);
  gemm64<0><<<dim3(NROWS / 64, 1), blk, 0, stream>>>(h2, dw2, db2, h1, NROWS, 64, 128,
      nullptr);
  gemm128<2><<<dim3(NROWS / 128, 4), blk, 0, stream>>>(h1, dw3, db3, nullptr,
      512, 64, nullptr, x, rparts);

  final_loss<<<dim3(1), blk, 0, stream>>>(qparts, NROWS / 4, rparts, 4096, out);
}